// Round 6
// baseline (439.779 us; speedup 1.0000x reference)
//
#include <hip/hip_runtime.h>
#include <hip/hip_bf16.h>

#define BT 1024
#define DD 1024
#define HH 2048
#define OO 1024
#define EE 8
#define RMAX 3072   // max padded rows (1024 tokens * 2 assignments, padded per expert)

typedef __bf16 bf16x8 __attribute__((ext_vector_type(8)));
typedef float  f32x4  __attribute__((ext_vector_type(4)));

// async global -> LDS, 16 bytes per lane. LDS dest must be wave-uniform base + lane*16.
__device__ __forceinline__ void cp16(void* l, const void* g) {
    __builtin_amdgcn_global_load_lds(
        (const __attribute__((address_space(1))) void*)g,
        (__attribute__((address_space(3))) void*)l, 16, 0, 0);
}

#define VMW(n)  asm volatile("s_waitcnt vmcnt(" #n ")" ::: "memory")
#define LGKM(n) asm volatile("s_waitcnt lgkmcnt(" #n ")" ::: "memory")
#define SCHED0  __builtin_amdgcn_sched_barrier(0)
#define BAR()   __builtin_amdgcn_s_barrier()

// ---------------- workspace layout (bytes) ----------------
// counts : int[8]              @ 0
// off    : int[9]              @ 256
// tok_e  : int[2048]           @ 1024
// tok_p  : int[2048]           @ 9216
// tok_w  : float[2048]         @ 17408
// elist  : int[8*1024]         @ 25600
// Xg     : bf16[3072*1024]     @ 65536       (end 6356992)
// H1     : bf16[3072*2048]     @ 6356992     (end 18939904)
// H2     : bf16[3072*2048]     @ 18939904    (end 31522816)
// Y      : f32 [3072*1024]     @ 31522816    (end 44105728)

// ---------------- router ----------------
__global__ __launch_bounds__(256) void router_kernel(
    const float* __restrict__ x, const float* __restrict__ Wr, const float* __restrict__ br,
    int* __restrict__ counts, int* __restrict__ elist,
    int* __restrict__ tok_e, int* __restrict__ tok_p, float* __restrict__ tok_w)
{
    int b = blockIdx.x;
    int tid = threadIdx.x;
    float acc[EE];
#pragma unroll
    for (int e = 0; e < EE; ++e) acc[e] = 0.f;
    const float* xr = x + (size_t)b * DD;
    for (int d = tid; d < DD; d += 256) {
        float xv = xr[d];
#pragma unroll
        for (int e = 0; e < EE; ++e) acc[e] += xv * Wr[d * EE + e];
    }
    __shared__ float red[4][EE];
    int lane = tid & 63, wv = tid >> 6;
#pragma unroll
    for (int e = 0; e < EE; ++e) {
        float v = acc[e];
#pragma unroll
        for (int o = 32; o > 0; o >>= 1) v += __shfl_down(v, o, 64);
        if (lane == 0) red[wv][e] = v;
    }
    __syncthreads();
    if (tid == 0) {
        float lg[EE];
#pragma unroll
        for (int e = 0; e < EE; ++e) lg[e] = red[0][e] + red[1][e] + red[2][e] + red[3][e] + br[e];
        float mx = lg[0];
#pragma unroll
        for (int e = 1; e < EE; ++e) mx = fmaxf(mx, lg[e]);
        float s = 0.f, p[EE];
#pragma unroll
        for (int e = 0; e < EE; ++e) { p[e] = expf(lg[e] - mx); s += p[e]; }
        float inv = 1.f / s;
#pragma unroll
        for (int e = 0; e < EE; ++e) p[e] *= inv;
        int i0 = 0; float b0 = p[0];
#pragma unroll
        for (int e = 1; e < EE; ++e) if (p[e] > b0) { b0 = p[e]; i0 = e; }
        int i1 = -1; float b1v = -1.f;
#pragma unroll
        for (int e = 0; e < EE; ++e) if (e != i0 && p[e] > b1v) { b1v = p[e]; i1 = e; }
        float s2 = b0 + b1v + 1e-6f;
        float w0 = b0 / s2, w1 = b1v / s2;
        int p0 = atomicAdd(&counts[i0], 1);
        int p1 = atomicAdd(&counts[i1], 1);
        elist[i0 * 1024 + p0] = b;
        elist[i1 * 1024 + p1] = b;
        tok_e[2 * b] = i0; tok_e[2 * b + 1] = i1;
        tok_p[2 * b] = p0; tok_p[2 * b + 1] = p1;
        tok_w[2 * b] = w0; tok_w[2 * b + 1] = w1;
    }
}

// ---------------- padded prefix sum ----------------
__global__ void offsets_kernel(const int* __restrict__ counts, int* __restrict__ off)
{
    if (threadIdx.x == 0 && blockIdx.x == 0) {
        int a = 0;
        for (int e = 0; e < EE; ++e) {
            off[e] = a;
            a += ((counts[e] + 127) >> 7) << 7;
        }
        off[EE] = a;
    }
}

// ---------------- gather x rows -> bf16, pad rows zeroed ----------------
__global__ __launch_bounds__(256) void gather_kernel(
    const float* __restrict__ x, const int* __restrict__ counts, const int* __restrict__ off,
    const int* __restrict__ elist, __bf16* __restrict__ Xg)
{
    int e = blockIdx.y;
    int chunk = blockIdx.x >> 2;
    int rg = blockIdx.x & 3;
    int cnt = counts[e];
    if (chunk * 128 >= cnt) return;
    int base = off[e] + chunk * 128 + rg * 32;
    int tid = threadIdx.x;
    for (int it = 0; it < 32; ++it) {
        int slot = chunk * 128 + rg * 32 + it;
        __bf16 v[4];
        if (slot < cnt) {
            int tok = elist[e * 1024 + slot];
            const float4 f = *(const float4*)(x + (size_t)tok * DD + tid * 4);
            v[0] = (__bf16)f.x; v[1] = (__bf16)f.y; v[2] = (__bf16)f.z; v[3] = (__bf16)f.w;
        } else {
            v[0] = v[1] = v[2] = v[3] = (__bf16)0.f;
        }
        *(uint2*)(Xg + (size_t)(base + it) * DD + tid * 4) = *(uint2*)v;
    }
}

// ---------------- fused full-K MFMA GEMM: Out = act(A * W[e] + bias) ----------------
// TM=64, TN=64, BK=32. Direct fp32 W reads (no prepass). R5's audited ledger,
// TM halved -> 2x active blocks (4/CU for g1/g2, 2/CU for g3) to attack the
// latency-bound cadence with TLP instead of per-block depth.
//  - A: 1 cp16/thread into 4 LDS bufs, slot-XOR image, issue distance 3.
//  - B: reg-staged fp32->bf16, parity double reg-set + parity LDS double buffer,
//    issue distance 2.
//  - ONE raw s_barrier per step. Steady-state VMW(9) retires exactly
//    {A(t+2) [1 cp16], B(t+1) [8 dwords]}; keeps {A(t+3), B(t+2)} in flight.
//  - Tail: VMW(8) at t==NS-3 (A-issues stopped), VMW(0) at t==NS-2.
// Grid: x = nt*8 + e (expert -> XCD pinning), y = mt (64-row tiles).
template <int K, int N, bool RELU, bool OUT_BF16>
__global__ __launch_bounds__(256, 4) void gemm_fused(
    const __bf16* __restrict__ A, const float* __restrict__ W,
    const float* __restrict__ bias, void* __restrict__ OutV,
    const int* __restrict__ counts, const int* __restrict__ off)
{
    constexpr int NSTEPS = K / 32;

    int e  = blockIdx.x & 7;
    int nt = blockIdx.x >> 3;
    int mt = blockIdx.y;
    int cnt = counts[e];
    if (mt * 64 >= cnt) return;
    int row0 = off[e] + mt * 64;

    const __bf16* Ab = A + (size_t)row0 * K;
    const float*  Wp = W + (size_t)e * K * N + nt * 64;

    __shared__ __bf16 As[4 * 2048];   // 4 bufs, [64 rows][32 k] (64B rows, slot-XOR image)
    __shared__ __bf16 Bs[2 * 2048];   // 2 bufs (parity), [64 n][32 k] (64B rows, slot-XOR image)

    int tid = threadIdx.x;
    int wave = tid >> 6, lane = tid & 63;
    int m = lane & 15, q = lane >> 4;
    int wm = (wave >> 1) * 32, wn = (wave & 1) * 32;

    // A-DMA: wave covers 16 rows; lane>>2 = row-in-16, lane&3 = slot.
    // Source k-chunk = slot ^ ((row>>1)&3) so LDS holds the slot-XOR image.
    int adr  = lane >> 2;
    int asrc = ((lane & 3) ^ ((lane >> 3) & 3)) * 8;

    // B-stage: thread owns column bn, 8 consecutive k's at bkc; one 16B LDS
    // store per step at the slot-XOR position.
    int bn = tid & 63;
    int bkc = (tid >> 6) * 8;
    int bslot = (bkc >> 3) ^ ((bn >> 1) & 3);

    float bA[8], bB[8];
    f32x4 acc[2][2] = {};

    auto issueA = [&](int t) {
        unsigned ab = (unsigned)(t & 3) * 2048;
        cp16(&As[ab + wave * 512 + lane * 8],
             Ab + (size_t)(wave * 16 + adr) * K + t * 32 + asrc);
    };
    auto loadB = [&](int t, float (&br_)[8]) {
        const float* p = Wp + (size_t)(t * 32 + bkc) * N + bn;   // 256B contiguous per wave per g
#pragma unroll
        for (int g = 0; g < 8; ++g) br_[g] = p[(size_t)g * N];
    };
    auto writeB = [&](int tw, float (&br_)[8]) {
        __attribute__((aligned(16))) __bf16 t8[8];
#pragma unroll
        for (int g = 0; g < 8; ++g) t8[g] = (__bf16)br_[g];
        *(uint4*)(&Bs[(unsigned)(tw & 1) * 2048 + bn * 32 + bslot * 8]) = *(uint4*)t8;
    };

    auto compute = [&](int t) {
        unsigned aR = (unsigned)(t & 3) * 2048;
        unsigned bR = (unsigned)(t & 1) * 2048;
        bf16x8 af[2], bfr[2];
#pragma unroll
        for (int i = 0; i < 2; ++i) {
            int row = wm + i * 16 + m;
            af[i] = *(bf16x8*)(&As[aR + row * 32 + (q ^ ((row >> 1) & 3)) * 8]);
        }
#pragma unroll
        for (int j = 0; j < 2; ++j) {
            int n = wn + j * 16 + m;
            bfr[j] = *(bf16x8*)(&Bs[bR + n * 32 + (q ^ ((n >> 1) & 3)) * 8]);
        }
        LGKM(0); SCHED0;
        __builtin_amdgcn_s_setprio(1);
#pragma unroll
        for (int i = 0; i < 2; ++i)
#pragma unroll
            for (int j = 0; j < 2; ++j)
                acc[i][j] = __builtin_amdgcn_mfma_f32_16x16x32_bf16(af[i], bfr[j], acc[i][j], 0, 0, 0);
        __builtin_amdgcn_s_setprio(0);
    };

    // prologue (queue after: [A1(1),B1(8),A2(1)] = 10 kept)
    issueA(0);
    loadB(0, bA);
    issueA(1);
    loadB(1, bB);
    issueA(2);
    VMW(10); SCHED0;            // retire A0,B0
    writeB(0, bA);
    LGKM(0);

    for (int t = 0; t < NSTEPS; t += 2) {
        // ---- even step t: read Bs[0]; write B(t+1) from bB; load B(t+2)->bA ----
        BAR(); SCHED0;
        if (t + 3 < NSTEPS) issueA(t + 3);
        if (t + 2 < NSTEPS) loadB(t + 2, bA);
        SCHED0;
        compute(t);
        if (t < NSTEPS - 3)      { VMW(9); }    // retire A(t+2),B(t+1); keep A(t+3),B(t+2)
        else                     { VMW(0); }    // t==NS-2: only B(t+1) left
        SCHED0;
        writeB(t + 1, bB);
        LGKM(0);

        // ---- odd step t+1: read Bs[1]; write B(t+2) from bA; load B(t+3)->bB ----
        BAR(); SCHED0;
        if (t + 4 < NSTEPS) issueA(t + 4);
        if (t + 3 < NSTEPS) loadB(t + 3, bB);
        SCHED0;
        compute(t + 1);
        if (t + 1 < NSTEPS - 1) {
            if (t + 1 < NSTEPS - 3)       { VMW(9); }
            else if (t + 1 == NSTEPS - 3) { VMW(8); }   // A-issues stopped; keep B(t+3)
            else                          { VMW(0); }
            SCHED0;
            writeB(t + 2, bA);
            LGKM(0);
        }
    }

    // epilogue: bias (+relu), store. D[row=q*4+r][col=m] per 16x16 subtile.
    const float* bp = bias + (size_t)e * N;
    int colbase = nt * 64 + wn;
#pragma unroll
    for (int j = 0; j < 2; ++j) {
        int col = colbase + j * 16 + m;
        float bv = bp[col];
#pragma unroll
        for (int i = 0; i < 2; ++i) {
            int rbase = row0 + wm + i * 16 + q * 4;
#pragma unroll
            for (int r = 0; r < 4; ++r) {
                float v = acc[i][j][r] + bv;
                if constexpr (RELU) v = fmaxf(v, 0.f);
                if constexpr (OUT_BF16)
                    ((__bf16*)OutV)[(size_t)(rbase + r) * N + col] = (__bf16)v;
                else
                    ((float*)OutV)[(size_t)(rbase + r) * N + col] = v;
            }
        }
    }
}

// ---------------- combine: out[b] = w0 * Y[r0] + w1 * Y[r1] (b3 folded into GEMM3) ----------------
__global__ __launch_bounds__(256) void combine_kernel(
    const float* __restrict__ Y, const int* __restrict__ off,
    const int* __restrict__ tok_e, const int* __restrict__ tok_p,
    const float* __restrict__ tok_w, float* __restrict__ out)
{
    int b = blockIdx.x, t = threadIdx.x;
    int e0 = tok_e[2 * b], e1 = tok_e[2 * b + 1];
    int r0 = off[e0] + tok_p[2 * b];
    int r1 = off[e1] + tok_p[2 * b + 1];
    float w0 = tok_w[2 * b], w1 = tok_w[2 * b + 1];
    int col = t * 4;
    f32x4 s0 = *(const f32x4*)(Y + (size_t)r0 * OO + col);
    f32x4 s1 = *(const f32x4*)(Y + (size_t)r1 * OO + col);
    f32x4 o = s0 * w0 + s1 * w1;
    *(f32x4*)(out + (size_t)b * OO + col) = o;
}

extern "C" void kernel_launch(void* const* d_in, const int* in_sizes, int n_in,
                              void* d_out, int out_size, void* d_ws, size_t ws_size,
                              hipStream_t stream)
{
    (void)in_sizes; (void)n_in; (void)out_size; (void)ws_size;
    const float* x  = (const float*)d_in[0];
    const float* Wr = (const float*)d_in[1];
    const float* br = (const float*)d_in[2];
    const float* W1 = (const float*)d_in[3];
    const float* b1 = (const float*)d_in[4];
    const float* W2 = (const float*)d_in[5];
    const float* b2 = (const float*)d_in[6];
    const float* W3 = (const float*)d_in[7];
    const float* b3 = (const float*)d_in[8];
    float* out = (float*)d_out;

    char* ws = (char*)d_ws;
    int*    counts = (int*)(ws + 0);
    int*    off    = (int*)(ws + 256);
    int*    tok_e  = (int*)(ws + 1024);
    int*    tok_p  = (int*)(ws + 9216);
    float*  tok_w  = (float*)(ws + 17408);
    int*    elist  = (int*)(ws + 25600);
    __bf16* Xg     = (__bf16*)(ws + 65536);
    __bf16* H1     = (__bf16*)(ws + 6356992);
    __bf16* H2     = (__bf16*)(ws + 18939904);
    float*  Y      = (float*)(ws + 31522816);

    hipMemsetAsync(counts, 0, 256, stream);
    router_kernel<<<1024, 256, 0, stream>>>(x, Wr, br, counts, elist, tok_e, tok_p, tok_w);
    offsets_kernel<<<1, 64, 0, stream>>>(counts, off);
    gather_kernel<<<dim3(32, 8), 256, 0, stream>>>(x, counts, off, elist, Xg);

    // TM=64 tiles: y = mt covers up to 1024 rows/expert
    gemm_fused<1024, 2048, true,  true ><<<dim3(256, 16), 256, 0, stream>>>(Xg, W1, b1, (void*)H1, counts, off);
    gemm_fused<2048, 2048, true,  true ><<<dim3(256, 16), 256, 0, stream>>>(H1, W2, b2, (void*)H2, counts, off);
    gemm_fused<2048, 1024, false, false><<<dim3(128, 16), 256, 0, stream>>>(H2, W3, b3, (void*)Y,  counts, off);

    combine_kernel<<<1024, 256, 0, stream>>>(Y, off, tok_e, tok_p, tok_w, out);
}